// Round 7
// baseline (191.930 us; speedup 1.0000x reference)
//
#include <hip/hip_runtime.h>

// SimpleRNN hidden=1: h_t = tanh(a*x_t + b*h_{t-1} + c), out = h_T per row.
// B=8192 rows x T=4096 steps, x fp32 [B,T] row-major.
//
// Structure (R6): one 256-thread block per row. Thread t owns chunk t
// (256 chunks x 16 steps). Stage the 16-KiB row to LDS with 4 coalesced
// dwordx4 per thread, read back per-thread chunks as ds_read_b128 through
// an XOR swizzle phys = s ^ ((s>>2)&7), 8-phase conflict-free on BOTH sides:
//   write s=i*256+t: quad = (t&7)^((t>>2)&7)  -> 8 distinct per 8 lanes
//   read  s=4t+q   : quad = (4(t&1)+q)^(t&7)  -> 8 distinct per 8 lanes
//
// R7 change (single variable): REVERT the nontemporal hint. R1's counters
// showed FETCH_SIZE=64 MiB for the 128-MiB x stream -> half of x is
// L3-resident from the harness's input restore, and WRITE_SIZE~0 -> no
// dirty-writeback penalty. NT (no-allocate) forfeits those L3 hits; plain
// loads take them. Expected kernel ~41 -> ~25-30 us.
//
// Math (absmax 0.0 in R2/R3/R4/R6): E = exp(2t); r = rcp(E+1); h = 1-2r;
//   E' = exp2(fma(r, nB4, q)), q = fma(x, A2, C2).
// Per chunk from h=0: G = chunk output, P = dF/dh|_0 = prod b*sech^2
// (post-step states; first pre-state factor skipped, final added at tail).
// Combine: affine maps compose associatively -> 6-step intra-wave shfl scan,
// then thread 0 composes the 4 wave totals (temporal order w=0..3).

constexpr int T_LEN = 4096;
constexpr int NTHR  = 256;
constexpr int CH    = T_LEN / NTHR;   // 16 steps per thread-chunk
constexpr int NF4   = CH / 4;         // 4 float4 per thread

typedef float fx4 __attribute__((ext_vector_type(4)));

__device__ __forceinline__ int swz(int s) { return s ^ ((s >> 2) & 7); }

#define STEP_PG(qv)                                                     \
    do {                                                                \
        float r_ = __builtin_amdgcn_rcpf(E + 1.0f);                     \
        P *= (fourb * r_) * (1.0f - r_);                                \
        E = __builtin_amdgcn_exp2f(fmaf(r_, nB4, (qv)));                \
    } while (0)

__global__ __launch_bounds__(NTHR)
void rnn_row_kernel(const float* __restrict__ x,
                    const float* __restrict__ w_ih,
                    const float* __restrict__ w_hh,
                    const float* __restrict__ b_ih,
                    const float* __restrict__ b_hh,
                    float* __restrict__ out) {
    __shared__ fx4 sm[T_LEN / 4];          // 16 KiB: one row
    __shared__ float wP[4], wG[4];         // per-wave affine totals

    const int tid  = threadIdx.x;
    const int lane = tid & 63;
    const int wv   = tid >> 6;
    const int row  = blockIdx.x;

    const float a  = w_ih[0];
    const float bb = w_hh[0];
    const float cc = b_ih[0] + b_hh[0];

    const float L2E2  = 2.88539008177792681472f;   // 2*log2(e)
    const float A2    = a * L2E2;
    const float C2    = (bb + cc) * L2E2;
    const float nB4   = -(bb * L2E2 * 2.0f);       // -4b*log2(e)
    const float fourb = 4.0f * bb;

    // --- Stage: 4 coalesced dwordx4 per thread -> swizzled LDS ---
    // Plain (allocating) loads: take the L3 hits on the resident half of x.
    const fx4* xp = (const fx4*)(x + (size_t)row * T_LEN);
#pragma unroll
    for (int i = 0; i < 4; ++i) {
        int s = i * NTHR + tid;
        sm[swz(s)] = xp[s];
    }
    __syncthreads();

    // --- Gather own 16-step chunk: 4 x ds_read_b128, 8-phase clean ---
    fx4 buf[NF4];
#pragma unroll
    for (int q = 0; q < NF4; ++q) buf[q] = sm[swz(tid * NF4 + q)];

    // --- 16-step chunk scan from h=0 with exact gain product ---
    float E, P = 1.0f;
    {
        fx4 v = buf[0];
        float q0 = fmaf(v.x, A2, C2);
        float q1 = fmaf(v.y, A2, C2);
        float q2 = fmaf(v.z, A2, C2);
        float q3 = fmaf(v.w, A2, C2);
        E = __builtin_amdgcn_exp2f(fmaf(0.5f, nB4, q0));  // h=0 => r=0.5 exact
        STEP_PG(q1); STEP_PG(q2); STEP_PG(q3);
    }
#pragma unroll
    for (int i = 1; i < NF4; ++i) {
        fx4 v = buf[i];
        float q0 = fmaf(v.x, A2, C2);
        float q1 = fmaf(v.y, A2, C2);
        float q2 = fmaf(v.z, A2, C2);
        float q3 = fmaf(v.w, A2, C2);
        STEP_PG(q0); STEP_PG(q1); STEP_PG(q2); STEP_PG(q3);
    }
    float r = __builtin_amdgcn_rcpf(E + 1.0f);
    float G = fmaf(-2.0f, r, 1.0f);
    P *= (fourb * r) * (1.0f - r);

    // --- Intra-wave inclusive affine scan (chunk order = lane order) ---
#pragma unroll
    for (int d = 1; d < 64; d <<= 1) {
        float Pl = __shfl_up(P, d, 64);
        float Gl = __shfl_up(G, d, 64);
        if (lane >= d) {
            G = fmaf(P, Gl, G);
            P *= Pl;
        }
    }
    if (lane == 63) { wP[wv] = P; wG[wv] = G; }
    __syncthreads();

    // --- Cross-wave composition, temporal order w=0..3; h0 = 0 ---
    if (tid == 0) {
        float h = wG[0];
        h = fmaf(wP[1], h, wG[1]);
        h = fmaf(wP[2], h, wG[2]);
        h = fmaf(wP[3], h, wG[3]);
        out[row] = h;
    }
}

extern "C" void kernel_launch(void* const* d_in, const int* in_sizes, int n_in,
                              void* d_out, int out_size, void* d_ws, size_t ws_size,
                              hipStream_t stream) {
    const float* x    = (const float*)d_in[0];
    const float* w_ih = (const float*)d_in[1];
    const float* w_hh = (const float*)d_in[2];
    const float* b_ih = (const float*)d_in[3];
    const float* b_hh = (const float*)d_in[4];
    float* out = (float*)d_out;

    const int B = out_size;                 // 8192 rows, one block per row
    dim3 grid(B), block(NTHR);
    rnn_row_kernel<<<grid, block, 0, stream>>>(x, w_ih, w_hh, b_ih, b_hh, out);
}

// Round 8
// 184.800 us; speedup vs baseline: 1.0386x; 1.0386x over previous
//
#include <hip/hip_runtime.h>

// SimpleRNN hidden=1: h_t = tanh(a*x_t + b*h_{t-1} + c), out = h_T per row.
// B=8192 rows x T=4096 steps, x fp32 [B,T] row-major.
//
// R8: persistent-ish blocks. Grid = 2048 blocks x 256 threads; block b owns
// rows 4b..4b+3 (contiguous 64 KiB). While computing row r from LDS, the
// next row r+1 is prefetched into registers with NT loads (latency ~900 cyc
// hidden under ~1.7K cyc of chain compute). Tests the hypothesis that R6's
// unexplained ~42 us (model: ~5-12 us) is workgroup ramp/lifecycle overhead
// from 8192 short-lived blocks with un-overlapped load->barrier->compute.
//
// Kept from R6 (best, 183.6 us; NT removal regressed to 191.9):
//  - NT loads (__builtin_nontemporal_load on ext_vector_type float4)
//  - XOR-swizzled LDS transpose phys = s ^ ((s>>2)&7), 8-phase clean both
//    sides (write s=i*256+t, read s=4t+q)
//  - E-formulation chain (absmax 0.0 in R2/R3/R4/R6/R7):
//      E = exp(2t); r = rcp(E+1); h = 1-2r; E' = exp2(fma(r, nB4, q)),
//      q = fma(x, A2, C2)
//  - per-chunk exact derivative P = prod b*sech^2 (post-step states; first
//    pre-state factor skipped, final state's factor added at tail)
//  - intra-wave 6-step affine shfl scan + cross-wave compose by thread 0.

constexpr int T_LEN = 4096;
constexpr int NTHR  = 256;
constexpr int CH    = T_LEN / NTHR;   // 16 steps per thread-chunk
constexpr int NF4   = CH / 4;         // 4 float4 per thread
constexpr int RPB   = 4;              // rows per block

typedef float fx4 __attribute__((ext_vector_type(4)));

__device__ __forceinline__ int swz(int s) { return s ^ ((s >> 2) & 7); }

#define STEP_PG(qv)                                                     \
    do {                                                                \
        float r_ = __builtin_amdgcn_rcpf(E + 1.0f);                     \
        P *= (fourb * r_) * (1.0f - r_);                                \
        E = __builtin_amdgcn_exp2f(fmaf(r_, nB4, (qv)));                \
    } while (0)

__global__ __launch_bounds__(NTHR)
void rnn_rows_kernel(const float* __restrict__ x,
                     const float* __restrict__ w_ih,
                     const float* __restrict__ w_hh,
                     const float* __restrict__ b_ih,
                     const float* __restrict__ b_hh,
                     float* __restrict__ out) {
    __shared__ fx4 sm[T_LEN / 4];          // 16 KiB: one row
    __shared__ float wP[4], wG[4];         // per-wave affine totals

    const int tid  = threadIdx.x;
    const int lane = tid & 63;
    const int wv   = tid >> 6;
    const int row0 = blockIdx.x * RPB;

    const float a  = w_ih[0];
    const float bb = w_hh[0];
    const float cc = b_ih[0] + b_hh[0];

    const float L2E2  = 2.88539008177792681472f;   // 2*log2(e)
    const float A2    = a * L2E2;
    const float C2    = (bb + cc) * L2E2;
    const float nB4   = -(bb * L2E2 * 2.0f);       // -4b*log2(e)
    const float fourb = 4.0f * bb;

    const fx4* xb = (const fx4*)(x + (size_t)row0 * T_LEN);

    // Initial prefetch: row0, 4 coalesced NT dwordx4 per thread.
    fx4 pf[4];
#pragma unroll
    for (int i = 0; i < 4; ++i)
        pf[i] = __builtin_nontemporal_load(&xb[i * NTHR + tid]);

    for (int it = 0; it < RPB; ++it) {
        // Stage prefetched row into swizzled LDS.
#pragma unroll
        for (int i = 0; i < 4; ++i) sm[swz(i * NTHR + tid)] = pf[i];
        __syncthreads();

        // Issue next row's NT loads now; latency hides under the chain.
        if (it + 1 < RPB) {
            const fx4* xn = xb + (size_t)(it + 1) * (T_LEN / 4);
#pragma unroll
            for (int i = 0; i < 4; ++i)
                pf[i] = __builtin_nontemporal_load(&xn[i * NTHR + tid]);
        }

        // Gather own 16-step chunk: 4 x ds_read_b128, 8-phase clean.
        fx4 buf[NF4];
#pragma unroll
        for (int q = 0; q < NF4; ++q) buf[q] = sm[swz(tid * NF4 + q)];

        // 16-step chunk scan from h=0 with exact gain product.
        float E, P = 1.0f;
        {
            fx4 v = buf[0];
            float q0 = fmaf(v.x, A2, C2);
            float q1 = fmaf(v.y, A2, C2);
            float q2 = fmaf(v.z, A2, C2);
            float q3 = fmaf(v.w, A2, C2);
            E = __builtin_amdgcn_exp2f(fmaf(0.5f, nB4, q0));  // h=0 => r=0.5
            STEP_PG(q1); STEP_PG(q2); STEP_PG(q3);
        }
#pragma unroll
        for (int i = 1; i < NF4; ++i) {
            fx4 v = buf[i];
            float q0 = fmaf(v.x, A2, C2);
            float q1 = fmaf(v.y, A2, C2);
            float q2 = fmaf(v.z, A2, C2);
            float q3 = fmaf(v.w, A2, C2);
            STEP_PG(q0); STEP_PG(q1); STEP_PG(q2); STEP_PG(q3);
        }
        float r = __builtin_amdgcn_rcpf(E + 1.0f);
        float G = fmaf(-2.0f, r, 1.0f);
        P *= (fourb * r) * (1.0f - r);

        // Intra-wave inclusive affine scan (chunk order = lane order).
#pragma unroll
        for (int d = 1; d < 64; d <<= 1) {
            float Pl = __shfl_up(P, d, 64);
            float Gl = __shfl_up(G, d, 64);
            if (lane >= d) {
                G = fmaf(P, Gl, G);
                P *= Pl;
            }
        }
        if (lane == 63) { wP[wv] = P; wG[wv] = G; }
        __syncthreads();

        // Cross-wave composition (temporal order w=0..3); h0 = 0.
        if (tid == 0) {
            float h = wG[0];
            h = fmaf(wP[1], h, wG[1]);
            h = fmaf(wP[2], h, wG[2]);
            h = fmaf(wP[3], h, wG[3]);
            out[row0 + it] = h;
        }
        __syncthreads();   // protect sm + wP/wG before next iteration
    }
}

extern "C" void kernel_launch(void* const* d_in, const int* in_sizes, int n_in,
                              void* d_out, int out_size, void* d_ws, size_t ws_size,
                              hipStream_t stream) {
    const float* x    = (const float*)d_in[0];
    const float* w_ih = (const float*)d_in[1];
    const float* w_hh = (const float*)d_in[2];
    const float* b_ih = (const float*)d_in[3];
    const float* b_hh = (const float*)d_in[4];
    float* out = (float*)d_out;

    const int B = out_size;                 // 8192 rows, 4 rows per block
    dim3 grid(B / RPB), block(NTHR);        // 2048 blocks
    rnn_rows_kernel<<<grid, block, 0, stream>>>(x, w_ih, w_hh, b_ih, b_hh, out);
}

// Round 9
// 184.328 us; speedup vs baseline: 1.0412x; 1.0026x over previous
//
#include <hip/hip_runtime.h>

// SimpleRNN hidden=1: h_t = tanh(a*x_t + b*h_{t-1} + c), out = h_T per row.
// B=8192 rows x T=4096 steps, x fp32 [B,T] row-major.
//
// R9: BARRIER-FREE WAVES + occupancy fix. Evidence: R6/R7/R8 plateau at
// kernel ~42 us ~= serialized sum of mem(21) + valu/trans(~15) + lds(5) --
// the load->__syncthreads->compute lockstep (barrier drains vmcnt(0) for
// every resident wave at once) prevents phase overlap; and VGPR=68 (R1) is
// just over the 64-VGPR cliff => only 4 waves/SIMD.
// Fixes, both from one observation: wave w's threads (64w..64w+63) read
// exactly the row-quarter [1024w,1024w+1024) that wave w itself stages ->
// the intra-row barrier was never needed.
//  - Each wave stages its own 4-KiB quarter (NT loads -> swizzled LDS; the
//    XOR swizzle only permutes bits 0-2, provably in-quarter), reads back,
//    computes. Per-wave vmcnt/lgkmcnt gives all ordering. Waves desync ->
//    memory-wait overlaps other waves' compute CU-wide.
//  - 4 rows per block, ONE __syncthreads at the end for the (P,G) compose.
//  - __launch_bounds__(256,8): force <=64 VGPR -> 8 waves/SIMD.
//
// Kept (absmax 0.0 in R2/R3/R4/R6/R7/R8): NT loads; swizzle
// phys = s ^ ((s>>2)&7) (8-phase conflict-free both sides); E-formulation
//   E = exp(2t); r = rcp(E+1); h = 1-2r; E' = exp2(fma(r, nB4, q)),
//   q = fma(x, A2, C2);
// per-chunk exact derivative P = prod b*sech^2 (post-step states; first
// pre-state factor skipped, final state's factor added at tail);
// intra-wave 6-step affine shfl scan; cross-wave compose in temporal order.

constexpr int T_LEN = 4096;
constexpr int NTHR  = 256;
constexpr int RPB   = 4;              // rows per block
constexpr int QF4   = 256;            // fx4 slots per wave-quarter (4 KiB)

typedef float fx4 __attribute__((ext_vector_type(4)));

__device__ __forceinline__ int swzl(int s) { return s ^ ((s >> 2) & 7); }

#define STEP_PG(qv)                                                     \
    do {                                                                \
        float r_ = __builtin_amdgcn_rcpf(E + 1.0f);                     \
        P *= (fourb * r_) * (1.0f - r_);                                \
        E = __builtin_amdgcn_exp2f(fmaf(r_, nB4, (qv)));                \
    } while (0)

__global__ __launch_bounds__(NTHR, 8)
void rnn_rows_kernel(const float* __restrict__ x,
                     const float* __restrict__ w_ih,
                     const float* __restrict__ w_hh,
                     const float* __restrict__ b_ih,
                     const float* __restrict__ b_hh,
                     float* __restrict__ out) {
    __shared__ fx4 sm[4][QF4];             // 16 KiB: one 4-KiB quarter per wave
    __shared__ float pgP[RPB][4], pgG[RPB][4];   // [row][wave] affine totals

    const int tid  = threadIdx.x;
    const int lane = tid & 63;
    const int wv   = tid >> 6;
    const int row0 = blockIdx.x * RPB;

    const float a  = w_ih[0];
    const float bb = w_hh[0];
    const float cc = b_ih[0] + b_hh[0];

    const float L2E2  = 2.88539008177792681472f;   // 2*log2(e)
    const float A2    = a * L2E2;
    const float C2    = (bb + cc) * L2E2;
    const float nB4   = -(bb * L2E2 * 2.0f);       // -4b*log2(e)
    const float fourb = 4.0f * bb;

    // Wave w's quarter of row r: fx4 index (row0+r)*1024 + w*256.
    const fx4* xq = (const fx4*)x + (size_t)row0 * (T_LEN / 4) + wv * QF4;

    for (int r = 0; r < RPB; ++r) {
        const fx4* xr = xq + (size_t)r * (T_LEN / 4);

        // Stage own quarter: 4 coalesced NT dwordx4 -> swizzled LDS.
        // Only this wave touches sm[wv]; per-wave vmcnt/lgkmcnt orders it.
#pragma unroll
        for (int i = 0; i < 4; ++i) {
            int s = i * 64 + lane;
            sm[wv][swzl(s)] = __builtin_nontemporal_load(&xr[s]);
        }

        // Gather own 16-step chunk: 4 x ds_read_b128, 8-phase clean.
        fx4 buf[4];
#pragma unroll
        for (int q = 0; q < 4; ++q) buf[q] = sm[wv][swzl(4 * lane + q)];

        // 16-step chunk scan from h=0 with exact gain product.
        float E, P = 1.0f;
        {
            fx4 v = buf[0];
            float q0 = fmaf(v.x, A2, C2);
            float q1 = fmaf(v.y, A2, C2);
            float q2 = fmaf(v.z, A2, C2);
            float q3 = fmaf(v.w, A2, C2);
            E = __builtin_amdgcn_exp2f(fmaf(0.5f, nB4, q0));  // h=0 => r=0.5
            STEP_PG(q1); STEP_PG(q2); STEP_PG(q3);
        }
#pragma unroll
        for (int i = 1; i < 4; ++i) {
            fx4 v = buf[i];
            float q0 = fmaf(v.x, A2, C2);
            float q1 = fmaf(v.y, A2, C2);
            float q2 = fmaf(v.z, A2, C2);
            float q3 = fmaf(v.w, A2, C2);
            STEP_PG(q0); STEP_PG(q1); STEP_PG(q2); STEP_PG(q3);
        }
        float rr = __builtin_amdgcn_rcpf(E + 1.0f);
        float G  = fmaf(-2.0f, rr, 1.0f);
        P *= (fourb * rr) * (1.0f - rr);

        // Intra-wave inclusive affine scan (chunk order = lane order).
#pragma unroll
        for (int d = 1; d < 64; d <<= 1) {
            float Pl = __shfl_up(P, d, 64);
            float Gl = __shfl_up(G, d, 64);
            if (lane >= d) {
                G = fmaf(P, Gl, G);
                P *= Pl;
            }
        }
        if (lane == 63) { pgP[r][wv] = P; pgG[r][wv] = G; }
        // No barrier: next iteration touches only this wave's own LDS/data.
    }

    __syncthreads();   // the ONLY block-wide barrier: publish pgP/pgG

    // Cross-wave composition (temporal order w=0..3); h0 = 0.
    if (tid < RPB) {
        float h = pgG[tid][0];
        h = fmaf(pgP[tid][1], h, pgG[tid][1]);
        h = fmaf(pgP[tid][2], h, pgG[tid][2]);
        h = fmaf(pgP[tid][3], h, pgG[tid][3]);
        out[row0 + tid] = h;
    }
}

extern "C" void kernel_launch(void* const* d_in, const int* in_sizes, int n_in,
                              void* d_out, int out_size, void* d_ws, size_t ws_size,
                              hipStream_t stream) {
    const float* x    = (const float*)d_in[0];
    const float* w_ih = (const float*)d_in[1];
    const float* w_hh = (const float*)d_in[2];
    const float* b_ih = (const float*)d_in[3];
    const float* b_hh = (const float*)d_in[4];
    float* out = (float*)d_out;

    const int B = out_size;                 // 8192 rows, 4 rows per block
    dim3 grid(B / RPB), block(NTHR);        // 2048 blocks
    rnn_rows_kernel<<<grid, block, 0, stream>>>(x, w_ih, w_hh, b_ih, b_hh, out);
}